// Round 22
// baseline (176.984 us; speedup 1.0000x reference)
//
#include <hip/hip_runtime.h>

#define QLEN 1024
#define KLEN 1024
#define BSZ 2
#define NHEAD 16
#define DHEAD 64
#define RS 2048            /* BSZ*NHEAD*DHEAD floats per seq row */
#define BLK_I 64
#define BLK_J 32
#define NT32 (KLEN / BLK_J)   /* 32 tiles per bn */
#define NBN (BSZ * NHEAD)
#define NQ (NBN * QLEN)

#define SC2f  0.18033688011112440f   /* 0.125 * log2(e) */
#define MBIGf 1.4426950408889634e30f /* 1e30 * log2(e)  */
#define THRf  8.0f                   /* defer-max threshold (log2 units) */

#define SEGP_BYTES  16777216u                     /* 2*64*32 subtiles x 4KB */
#define KT_BYTES    ((size_t)NBN * NT32 * 4096)   /* 4 MiB per tensor */
#define OPART1_BYTES 4194304u                     /* NBN*QLEN*64*2 (bf16)   */
#define ML1_BYTES    262144u                      /* NBN*QLEN*2*4           */

typedef __attribute__((ext_vector_type(8))) short s16x8;
typedef __attribute__((ext_vector_type(4))) short s16x4;
typedef __attribute__((ext_vector_type(8))) unsigned short u16x8;
typedef __attribute__((ext_vector_type(4))) unsigned short u16x4;
typedef __attribute__((ext_vector_type(4))) float f32x4;

__device__ __forceinline__ unsigned short f2bf(float f) {
    union { float f; unsigned int u; } x; x.f = f;
    unsigned int r = x.u + 0x7fffu + ((x.u >> 16) & 1u);
    return (unsigned short)(r >> 16);
}
__device__ __forceinline__ float bf2f(unsigned short h) {
    union { unsigned int u; float f; } x; x.u = ((unsigned int)h) << 16;
    return x.f;
}

__device__ __forceinline__ f32x4 mfma16x16x16(s16x4 a, s16x4 b, f32x4 c) {
#if __has_builtin(__builtin_amdgcn_mfma_f32_16x16x16bf16_1k)
    return __builtin_amdgcn_mfma_f32_16x16x16bf16_1k(a, b, c, 0, 0, 0);
#else
    f32x4 d;
    asm("v_mfma_f32_16x16x16_bf16 %0, %1, %2, %3"
        : "=v"(d) : "v"(a), "v"(b), "0"(c));
    return d;
#endif
}

typedef const __attribute__((address_space(1))) unsigned int* gas_t;
typedef __attribute__((address_space(3))) unsigned int* las_t;
__device__ __forceinline__ void gl_lds16(const void* g, void* l) {
    __builtin_amdgcn_global_load_lds((gas_t)g, (las_t)l, 16, 0, 0);
}

// ---- fused pre-pass: seg + K/Kr verbatim R21; V packed in CONSUMPTION order -
// V tile (4KB per (bn,jt)): u16 pos = tid*8; tid = dt*64 + lane;
//   contents: e<4 -> V[j = q4*4+e][d = dt*16+c];  e>=4 -> V[j = 16+q4*4+(e-4)][d]
__global__ __launch_bounds__(256)
void pack_all_kernel(const float* __restrict__ segmat,
                     const float* __restrict__ mask,
                     const float* __restrict__ kh,
                     const float* __restrict__ kr,
                     const float* __restrict__ v,
                     unsigned short* __restrict__ segT,
                     unsigned short* __restrict__ Kp,
                     unsigned short* __restrict__ Krp,
                     unsigned short* __restrict__ Vtp)
{
    __shared__ float smS[16][32][4];
    __shared__ float smM[16][33];
    __shared__ float VT[32][65];
    const int bid = blockIdx.x;
    const int tid = threadIdx.x;

    if (bid < 2048) {
        const int istrip = bid >> 5;
        const int jt     = bid & 31;
        const int ib     = istrip * 16;
        const int jb     = jt * 32;
        {
            const int il = tid >> 4;
            const int j2 = (tid & 15) * 2;
            const float* sp = segmat + ((size_t)(ib + il) * KLEN + jb + j2) * 4;
            *(f32x4*)&smS[il][j2][0]     = *(const f32x4*)sp;
            *(f32x4*)&smS[il][j2 + 1][0] = *(const f32x4*)(sp + 4);
            const float* mp = mask + (size_t)(ib + il) * KLEN + jb + j2;
            smM[il][j2]     = mp[0] * MBIGf;
            smM[il][j2 + 1] = mp[1] * MBIGf;
        }
        __syncthreads();
        const int k  = tid >> 6;
        const int l  = tid & 63;
        const int q4 = l >> 4;
        const int il = l & 15;
        const int jl = (k >> 1) * 16 + q4 * 4 + (k & 1) * 2;
#pragma unroll
        for (int b = 0; b < 2; ++b) {
            u16x8 o;
#pragma unroll
            for (int e = 0; e < 2; ++e) {
                o[e * 4 + 0] = f2bf(smS[il][jl + e][b * 2]);
                o[e * 4 + 1] = f2bf(smS[il][jl + e][b * 2 + 1]);
                o[e * 4 + 2] = f2bf(smM[il][jl + e]);
                o[e * 4 + 3] = 0;
            }
            unsigned short* op = segT + ((size_t)(b * 64 + istrip) << 16)
                                 + (jt << 11) + tid * 8;
            *(u16x8*)op = o;
        }
    } else {
        const int blk = bid - 2048;               // bn*NT32 + jt
        const int bn  = blk >> 5;
        const int jt  = blk & (NT32 - 1);
        const int b   = bn & 1;
        const int n   = bn >> 1;
        const int boff = b * NHEAD * DHEAD + n * DHEAD;
        const int j0  = jt * BLK_J;

        {
            const int j  = tid >> 3;
            const int dq = (tid & 7) * 8;
            const float* vp = v + (size_t)(j0 + j) * RS + boff + dq;
#pragma unroll
            for (int e = 0; e < 8; ++e) VT[j][dq + e] = vp[e];
        }
        __syncthreads();

        const size_t tb = (size_t)blk * 2048;
        {
            const int row = tid >> 3;
            const int ch  = (tid & 7) ^ (row & 7);
            u16x8 ok, orr;
            const float* hp = kh + (size_t)(j0 + row) * RS + boff + ch * 8;
            const float* rp = kr + (size_t)(j0 + row + 1) * RS + boff + ch * 8; // shift +1
#pragma unroll
            for (int e = 0; e < 8; ++e) { ok[e] = f2bf(hp[e]); orr[e] = f2bf(rp[e]); }
            *(u16x8*)&Kp [tb + (size_t)tid * 8] = ok;
            *(u16x8*)&Krp[tb + (size_t)tid * 8] = orr;
        }
        {   // V consumption-order pack
            const int dt = tid >> 6;
            const int l  = tid & 63;
            const int q4v = l >> 4;
            const int cv  = l & 15;
            const int d   = dt * 16 + cv;
            u16x8 ov;
#pragma unroll
            for (int js = 0; js < 2; ++js)
#pragma unroll
                for (int e = 0; e < 4; ++e)
                    ov[js * 4 + e] = f2bf(VT[js * 16 + q4v * 4 + e][d]);
            *(u16x8*)&Vtp[tb + (size_t)tid * 8] = ov;
        }
    }
}

// ---- merge: combine jsp j-slice bf16 partials -------------------------------
__global__ __launch_bounds__(256)
void merge_kernel(const unsigned short* __restrict__ opart,
                  const float* __restrict__ ml,
                  float* __restrict__ out, int jsp)
{
    const int gid = blockIdx.x * 256 + threadIdx.x;   // NQ*64 items
    const int d   = gid & 63;
    const int rr  = gid >> 6;                          // (b*NHEAD+n)*QLEN + i
    const int i   = rr & (QLEN - 1);
    const int n   = (rr >> 10) & (NHEAD - 1);
    const int b   = rr >> 14;
    float M = -INFINITY;
    for (int p = 0; p < jsp; ++p)
        M = fmaxf(M, ml[(size_t)(p * NQ + rr) * 2]);
    float L = 0.f, O = 0.f;
    for (int p = 0; p < jsp; ++p) {
        const float w = __builtin_amdgcn_exp2f(ml[(size_t)(p * NQ + rr) * 2] - M);
        L += ml[(size_t)(p * NQ + rr) * 2 + 1] * w;
        O += bf2f(opart[(size_t)(p * NQ + rr) * 64 + d]) * w;
    }
    out[(size_t)i * RS + b * NHEAD * DHEAD + n * DHEAD + d] = O / L;
}

// ---- main: zero-LDS V (regs from global), 16KB LDS, up to 8 blocks/CU -------
__global__ __launch_bounds__(256, 8)
void relattn_kernel(const float* __restrict__ q,
                    const float* __restrict__ segemb,
                    const float* __restrict__ rwb,
                    const float* __restrict__ rrb,
                    const float* __restrict__ rsb,
                    const unsigned short* __restrict__ segT,
                    const unsigned short* __restrict__ Kp,
                    const unsigned short* __restrict__ Krp,
                    const unsigned short* __restrict__ Vtp,
                    unsigned short* __restrict__ opart,
                    float* __restrict__ mlpart,
                    float* __restrict__ out,
                    int lg, int njt)
{
    __shared__ unsigned short KhL[2][32][64];
    __shared__ unsigned short KrL[2][32][64];

    const int jsp = 1 << lg;
    // XCD grouping: heads of one (b,i0,jspq) share one XCD's L2 seg region
    const int F = blockIdx.x;            // 512*jsp blocks
    const int x = F & 7;
    const int k = F >> 3;
    const int n = k & 15;
    const int g = ((k >> 4) << 3) + x;   // 0..32*jsp-1
    const int jspq = g & (jsp - 1);
    const int t2 = g >> lg;              // 0..31
    const int b  = t2 & 1;
    const int i0 = (t2 >> 1) * BLK_I;
    const int bn = n * 2 + b;            // matches pack layout
    const int boff = b * NHEAD * DHEAD + n * DHEAD;

    const int tid  = threadIdx.x;
    const int wave = tid >> 6;
    const int lane = tid & 63;
    const int q4   = lane >> 4;
    const int c    = lane & 15;
    const int iRow = i0 + wave * 16 + c;

    // ---- Q fragments (SC2f folded) + in-lane ef0 ----
    s16x8 qwf[2], qrf[2];
    float e0, e1;
    {
        const float* qp = q + (size_t)iRow * RS + boff;
        float es0 = 0.f, es1 = 0.f;
#pragma unroll
        for (int kk = 0; kk < 2; ++kk) {
            const int off = kk * 32 + q4 * 8;
            const f32x4 q0 = *(const f32x4*)(qp + off);
            const f32x4 q1 = *(const f32x4*)(qp + off + 4);
            const f32x4 w0 = *(const f32x4*)(rwb + n * DHEAD + off);
            const f32x4 w1 = *(const f32x4*)(rwb + n * DHEAD + off + 4);
            const f32x4 r0 = *(const f32x4*)(rrb + n * DHEAD + off);
            const f32x4 r1 = *(const f32x4*)(rrb + n * DHEAD + off + 4);
            const f32x4 sa = *(const f32x4*)(segemb + n * DHEAD + off);
            const f32x4 sb = *(const f32x4*)(segemb + n * DHEAD + off + 4);
            const f32x4 ta = *(const f32x4*)(segemb + (NHEAD + n) * DHEAD + off);
            const f32x4 tb = *(const f32x4*)(segemb + (NHEAD + n) * DHEAD + off + 4);
            const f32x4 ra = *(const f32x4*)(rsb + n * DHEAD + off);
            const f32x4 rb = *(const f32x4*)(rsb + n * DHEAD + off + 4);
            s16x8 tw, tr;
#pragma unroll
            for (int e = 0; e < 4; ++e) {
                tw[e]     = (short)f2bf((q0[e] + w0[e]) * SC2f);
                tw[4 + e] = (short)f2bf((q1[e] + w1[e]) * SC2f);
                tr[e]     = (short)f2bf((q0[e] + r0[e]) * SC2f);
                tr[4 + e] = (short)f2bf((q1[e] + r1[e]) * SC2f);
                es0 += (q0[e] + ra[e]) * sa[e] + (q1[e] + rb[e]) * sb[e];
                es1 += (q0[e] + ra[e]) * ta[e] + (q1[e] + rb[e]) * tb[e];
            }
            qwf[kk] = tw; qrf[kk] = tr;
        }
        es0 += __shfl_xor(es0, 16, 64); es0 += __shfl_xor(es0, 32, 64);
        es1 += __shfl_xor(es1, 16, 64); es1 += __shfl_xor(es1, 32, 64);
        e0 = es0 * SC2f; e1 = es1 * SC2f;
    }

    const int tbase = bn * NT32 + jspq * njt;
    auto stage = [&](int jt, int buf) {
        const size_t toff = ((size_t)(tbase + jt)) << 12;
        const int go = tid * 16;
        const int lo = wave * 1024;
        gl_lds16((const char*)Kp  + toff + go, (char*)&KhL[buf][0][0] + lo);
        gl_lds16((const char*)Krp + toff + go, (char*)&KrL[buf][0][0] + lo);
    };

    stage(0, 0);
    __syncthreads();

    float m = -INFINITY, lsum = 0.f;
    f32x4 acc[4];
#pragma unroll
    for (int dt = 0; dt < 4; ++dt) acc[dt] = (f32x4)0.f;

    // per-wave coalesced seg subtile base: (b, istrip = i0/16 + wave)
    const unsigned short* segW = segT + ((size_t)(b * 64 + (i0 >> 4) + wave) << 16);

    int cur = 0;
    for (int jt = 0; jt < njt; ++jt) {
        if (jt + 1 < njt) stage(jt + 1, cur ^ 1);   // K/Kr DMA flies under compute

        // ---- seg/mask: 4 coalesced 1KB wave-loads ----
        const unsigned short* st = segW + ((jspq * njt + jt) << 11);
        u16x8 pg[4];
        pg[0] = *(const u16x8*)(st + lane * 8);
        pg[1] = *(const u16x8*)(st + 512 + lane * 8);
        pg[2] = *(const u16x8*)(st + 1024 + lane * 8);
        pg[3] = *(const u16x8*)(st + 1536 + lane * 8);

        // ---- V fragments straight from global (consumption-order pack) ----
        const unsigned short* vtb = Vtp + (((size_t)(tbase + jt)) << 11);
        u16x8 vg[4];
#pragma unroll
        for (int dt = 0; dt < 4; ++dt)
            vg[dt] = *(const u16x8*)(vtb + ((dt << 6) + lane) * 8);

        // ---- S^T = (Kh Qw^T + Kr Qr^T): D[j][i], lane holds row i=c ----
        f32x4 sjT[2];
        sjT[0] = (f32x4)0.f; sjT[1] = (f32x4)0.f;
        __builtin_amdgcn_s_setprio(1);
#pragma unroll
        for (int kk = 0; kk < 2; ++kk)
#pragma unroll
            for (int js = 0; js < 2; ++js) {
                const int row = js * 16 + c;
                const int pcK = ((kk * 4 + q4) ^ (c & 7)) * 8;
                const s16x8 khf = *(const s16x8*)&KhL[cur][row][pcK];
                const s16x8 krf = *(const s16x8*)&KrL[cur][row][pcK];
                sjT[js] = __builtin_amdgcn_mfma_f32_16x16x32_bf16(khf, qwf[kk], sjT[js], 0, 0, 0);
                sjT[js] = __builtin_amdgcn_mfma_f32_16x16x32_bf16(krf, qrf[kk], sjT[js], 0, 0, 0);
            }
        __builtin_amdgcn_s_setprio(0);

        // ---- bias (SC2f pre-folded) ----
        float sc8[8];
#pragma unroll
        for (int js = 0; js < 2; ++js)
#pragma unroll
            for (int r = 0; r < 4; ++r) {
                const u16x8 g2 = pg[js * 2 + (r >> 1)];
                const int bb = (r & 1) * 4;
                sc8[js * 4 + r] = sjT[js][r]
                                  + bf2f(g2[bb]) * e0 + bf2f(g2[bb + 1]) * e1
                                  - bf2f(g2[bb + 2]);
            }
        float pmax = fmaxf(
            fmaxf(fmaxf(sc8[0], sc8[1]), fmaxf(sc8[2], sc8[3])),
            fmaxf(fmaxf(sc8[4], sc8[5]), fmaxf(sc8[6], sc8[7])));

        // ---- defer-max (T13) ----
        if (!__all(pmax <= m + THRf)) {
            float mt = pmax;
            mt = fmaxf(mt, __shfl_xor(mt, 16, 64));
            mt = fmaxf(mt, __shfl_xor(mt, 32, 64));
            const float mn  = fmaxf(m, mt);
            const float scl = __builtin_amdgcn_exp2f(m - mn);
            m = mn;
            lsum *= scl;
#pragma unroll
            for (int dt = 0; dt < 4; ++dt) acc[dt] *= scl;
        }

        // ---- P = exp2(sc - m) ----
        float p[8], ps = 0.f;
#pragma unroll
        for (int e = 0; e < 8; ++e) {
            p[e] = __builtin_amdgcn_exp2f(sc8[e] - m);
            ps += p[e];
        }
        lsum += ps;   // per-lane q4-partial; reduced at epilogue

        // ---- zero-exchange PV (k=16), V operand already in registers ----
        s16x4 pf4[2];
#pragma unroll
        for (int js = 0; js < 2; ++js) {
            union { unsigned int w[2]; s16x4 v; } pk2;
            asm("v_cvt_pk_bf16_f32 %0, %1, %2" : "=v"(pk2.w[0]) : "v"(p[js*4+0]), "v"(p[js*4+1]));
            asm("v_cvt_pk_bf16_f32 %0, %1, %2" : "=v"(pk2.w[1]) : "v"(p[js*4+2]), "v"(p[js*4+3]));
            pf4[js] = pk2.v;
        }
        __builtin_amdgcn_s_setprio(1);
#pragma unroll
        for (int dt = 0; dt < 4; ++dt) {
            union { u16x8 w; s16x4 h[2]; } vv; vv.w = vg[dt];
#pragma unroll
            for (int js = 0; js < 2; ++js)
                acc[dt] = mfma16x16x16(vv.h[js], pf4[js], acc[dt]);
        }
        __builtin_amdgcn_s_setprio(0);

        __syncthreads();   // drains DMA + all waves done with buf[cur]
        cur ^= 1;
    }

    // ---- full-row lsum (reduce over q4 groups) ----
    lsum += __shfl_xor(lsum, 16, 64);
    lsum += __shfl_xor(lsum, 32, 64);

    // ---- store ----
    if (lg) {
        const int rowG = ((jspq * BSZ + b) * NHEAD + n) * QLEN + iRow;
#pragma unroll
        for (int dt = 0; dt < 4; ++dt) {
            u16x4 ob;
#pragma unroll
            for (int e = 0; e < 4; ++e) ob[e] = f2bf(acc[dt][e]);
            *(u16x4*)&opart[(size_t)rowG * 64 + dt * 16 + q4 * 4] = ob;
        }
        if (q4 == 0) {
            mlpart[(size_t)rowG * 2]     = m;
            mlpart[(size_t)rowG * 2 + 1] = lsum;
        }
    } else {
        const float inv = 1.f / lsum;
        float* op = out + (size_t)iRow * RS + boff;
#pragma unroll
        for (int dt = 0; dt < 4; ++dt) {
            const f32x4 o = acc[dt] * inv;
            *(f32x4*)&op[dt * 16 + q4 * 4] = o;
        }
    }
}

extern "C" void kernel_launch(void* const* d_in, const int* in_sizes, int n_in,
                              void* d_out, int out_size, void* d_ws, size_t ws_size,
                              hipStream_t stream) {
    const float* q   = (const float*)d_in[0];
    const float* kh  = (const float*)d_in[1];
    const float* v   = (const float*)d_in[2];
    const float* kr  = (const float*)d_in[3];
    const float* se  = (const float*)d_in[4];
    const float* sm  = (const float*)d_in[5];
    const float* rwb = (const float*)d_in[6];
    const float* rrb = (const float*)d_in[7];
    const float* rsb = (const float*)d_in[8];
    const float* msk = (const float*)d_in[9];
    float* out = (float*)d_out;

    char* wsb = (char*)d_ws;
    unsigned short* segT = (unsigned short*)wsb;
    unsigned short* Kp   = (unsigned short*)(wsb + SEGP_BYTES);
    unsigned short* Krp  = (unsigned short*)(wsb + SEGP_BYTES + KT_BYTES);
    unsigned short* Vtp  = (unsigned short*)(wsb + SEGP_BYTES + 2 * KT_BYTES);
    unsigned short* opart = (unsigned short*)(wsb + SEGP_BYTES + 3 * KT_BYTES);

    const size_t base = (size_t)SEGP_BYTES + 3 * KT_BYTES;
    int lg = 0;
    if (ws_size >= base + 4 * ((size_t)OPART1_BYTES + ML1_BYTES))      lg = 2;
    else if (ws_size >= base + 2 * ((size_t)OPART1_BYTES + ML1_BYTES)) lg = 1;
    const int jsp = 1 << lg;
    const int njt = NT32 >> lg;
    float* mlpart = (float*)(wsb + base + (size_t)jsp * OPART1_BYTES);

    pack_all_kernel<<<2048 + NBN * NT32, 256, 0, stream>>>(sm, msk, kh, kr, v,
                                                           segT, Kp, Krp, Vtp);
    relattn_kernel<<<512 * jsp, 256, 0, stream>>>(q, se, rwb, rrb, rsb,
                                                  segT, Kp, Krp, Vtp,
                                                  opart, mlpart, out, lg, njt);
    if (lg)
        merge_kernel<<<NQ * DHEAD / 256, 256, 0, stream>>>(opart, mlpart, out, jsp);
}

// Round 23
// 60.492 us; speedup vs baseline: 2.9257x; 2.9257x over previous
//
#include <hip/hip_runtime.h>

#define QLEN 1024
#define KLEN 1024
#define BSZ 2
#define NHEAD 16
#define DHEAD 64
#define RS 2048            /* BSZ*NHEAD*DHEAD floats per seq row */
#define BLK_I 64
#define BLK_J 32
#define NT32 (KLEN / BLK_J)   /* 32 tiles per bn */
#define NBN (BSZ * NHEAD)
#define NQ (NBN * QLEN)

#define SC2f  0.18033688011112440f   /* 0.125 * log2(e) */
#define MBIGf 1.4426950408889634e30f /* 1e30 * log2(e)  */
#define THRf  8.0f                   /* defer-max threshold (log2 units) */

#define SEGP_BYTES  16777216u                     /* 2*64*32 subtiles x 4KB */
#define KT_BYTES    ((size_t)NBN * NT32 * 4096)   /* 4 MiB per tensor */
#define OPART1_BYTES 4194304u                     /* NBN*QLEN*64*2 (bf16)   */
#define ML1_BYTES    262144u                      /* NBN*QLEN*2*4           */

typedef __attribute__((ext_vector_type(8))) short s16x8;
typedef __attribute__((ext_vector_type(4))) short s16x4;
typedef __attribute__((ext_vector_type(8))) unsigned short u16x8;
typedef __attribute__((ext_vector_type(4))) unsigned short u16x4;
typedef __attribute__((ext_vector_type(4))) float f32x4;

__device__ __forceinline__ unsigned short f2bf(float f) {
    union { float f; unsigned int u; } x; x.f = f;
    unsigned int r = x.u + 0x7fffu + ((x.u >> 16) & 1u);
    return (unsigned short)(r >> 16);
}
__device__ __forceinline__ float bf2f(unsigned short h) {
    union { unsigned int u; float f; } x; x.u = ((unsigned int)h) << 16;
    return x.f;
}

__device__ __forceinline__ f32x4 mfma16x16x16(s16x4 a, s16x4 b, f32x4 c) {
#if __has_builtin(__builtin_amdgcn_mfma_f32_16x16x16bf16_1k)
    return __builtin_amdgcn_mfma_f32_16x16x16bf16_1k(a, b, c, 0, 0, 0);
#else
    f32x4 d;
    asm("v_mfma_f32_16x16x16_bf16 %0, %1, %2, %3"
        : "=v"(d) : "v"(a), "v"(b), "0"(c));
    return d;
#endif
}

typedef const __attribute__((address_space(1))) unsigned int* gas_t;
typedef __attribute__((address_space(3))) unsigned int* las_t;
__device__ __forceinline__ void gl_lds16(const void* g, void* l) {
    __builtin_amdgcn_global_load_lds((gas_t)g, (las_t)l, 16, 0, 0);
}

// ---- fused pre-pass (verbatim round-22, passed) -----------------------------
__global__ __launch_bounds__(256)
void pack_all_kernel(const float* __restrict__ segmat,
                     const float* __restrict__ mask,
                     const float* __restrict__ kh,
                     const float* __restrict__ kr,
                     const float* __restrict__ v,
                     unsigned short* __restrict__ segT,
                     unsigned short* __restrict__ Kp,
                     unsigned short* __restrict__ Krp,
                     unsigned short* __restrict__ Vtp)
{
    __shared__ float smS[16][32][4];
    __shared__ float smM[16][33];
    __shared__ float VT[32][65];
    const int bid = blockIdx.x;
    const int tid = threadIdx.x;

    if (bid < 2048) {
        const int istrip = bid >> 5;
        const int jt     = bid & 31;
        const int ib     = istrip * 16;
        const int jb     = jt * 32;
        {
            const int il = tid >> 4;
            const int j2 = (tid & 15) * 2;
            const float* sp = segmat + ((size_t)(ib + il) * KLEN + jb + j2) * 4;
            *(f32x4*)&smS[il][j2][0]     = *(const f32x4*)sp;
            *(f32x4*)&smS[il][j2 + 1][0] = *(const f32x4*)(sp + 4);
            const float* mp = mask + (size_t)(ib + il) * KLEN + jb + j2;
            smM[il][j2]     = mp[0] * MBIGf;
            smM[il][j2 + 1] = mp[1] * MBIGf;
        }
        __syncthreads();
        const int k  = tid >> 6;
        const int l  = tid & 63;
        const int q4 = l >> 4;
        const int il = l & 15;
        const int jl = (k >> 1) * 16 + q4 * 4 + (k & 1) * 2;
#pragma unroll
        for (int b = 0; b < 2; ++b) {
            u16x8 o;
#pragma unroll
            for (int e = 0; e < 2; ++e) {
                o[e * 4 + 0] = f2bf(smS[il][jl + e][b * 2]);
                o[e * 4 + 1] = f2bf(smS[il][jl + e][b * 2 + 1]);
                o[e * 4 + 2] = f2bf(smM[il][jl + e]);
                o[e * 4 + 3] = 0;
            }
            unsigned short* op = segT + ((size_t)(b * 64 + istrip) << 16)
                                 + (jt << 11) + tid * 8;
            *(u16x8*)op = o;
        }
    } else {
        const int blk = bid - 2048;               // bn*NT32 + jt
        const int bn  = blk >> 5;
        const int jt  = blk & (NT32 - 1);
        const int b   = bn & 1;
        const int n   = bn >> 1;
        const int boff = b * NHEAD * DHEAD + n * DHEAD;
        const int j0  = jt * BLK_J;

        {
            const int j  = tid >> 3;
            const int dq = (tid & 7) * 8;
            const float* vp = v + (size_t)(j0 + j) * RS + boff + dq;
#pragma unroll
            for (int e = 0; e < 8; ++e) VT[j][dq + e] = vp[e];
        }
        __syncthreads();

        const size_t tb = (size_t)blk * 2048;
        {
            const int row = tid >> 3;
            const int ch  = (tid & 7) ^ (row & 7);
            u16x8 ok, orr;
            const float* hp = kh + (size_t)(j0 + row) * RS + boff + ch * 8;
            const float* rp = kr + (size_t)(j0 + row + 1) * RS + boff + ch * 8; // shift +1
#pragma unroll
            for (int e = 0; e < 8; ++e) { ok[e] = f2bf(hp[e]); orr[e] = f2bf(rp[e]); }
            *(u16x8*)&Kp [tb + (size_t)tid * 8] = ok;
            *(u16x8*)&Krp[tb + (size_t)tid * 8] = orr;
        }
        {   // V consumption-order pack: pos = tid*8, tid = dt*64 + lane
            const int dt = tid >> 6;
            const int l  = tid & 63;
            const int q4v = l >> 4;
            const int cv  = l & 15;
            const int d   = dt * 16 + cv;
            u16x8 ov;
#pragma unroll
            for (int js = 0; js < 2; ++js)
#pragma unroll
                for (int e = 0; e < 4; ++e)
                    ov[js * 4 + e] = f2bf(VT[js * 16 + q4v * 4 + e][d]);
            *(u16x8*)&Vtp[tb + (size_t)tid * 8] = ov;
        }
    }
}

// ---- merge: combine jsp j-slice bf16 partials (round-22 body, passed) -------
__global__ __launch_bounds__(256)
void merge_kernel(const unsigned short* __restrict__ opart,
                  const float* __restrict__ ml,
                  float* __restrict__ out, int jsp)
{
    const int gid = blockIdx.x * 256 + threadIdx.x;   // NQ*64 items
    const int d   = gid & 63;
    const int rr  = gid >> 6;                          // (b*NHEAD+n)*QLEN + i
    const int i   = rr & (QLEN - 1);
    const int n   = (rr >> 10) & (NHEAD - 1);
    const int b   = rr >> 14;
    float M = -INFINITY;
    for (int p = 0; p < jsp; ++p)
        M = fmaxf(M, ml[(size_t)(p * NQ + rr) * 2]);
    float L = 0.f, O = 0.f;
    for (int p = 0; p < jsp; ++p) {
        const float w = __builtin_amdgcn_exp2f(ml[(size_t)(p * NQ + rr) * 2] - M);
        L += ml[(size_t)(p * NQ + rr) * 2 + 1] * w;
        O += bf2f(opart[(size_t)(p * NQ + rr) * 64 + d]) * w;
    }
    out[(size_t)i * RS + b * NHEAD * DHEAD + n * DHEAD + d] = O / L;
}

// ---- main: R22 structure at SANE bounds (256,4) — no spill ------------------
__global__ __launch_bounds__(256, 4)
void relattn_kernel(const float* __restrict__ q,
                    const float* __restrict__ segemb,
                    const float* __restrict__ rwb,
                    const float* __restrict__ rrb,
                    const float* __restrict__ rsb,
                    const unsigned short* __restrict__ segT,
                    const unsigned short* __restrict__ Kp,
                    const unsigned short* __restrict__ Krp,
                    const unsigned short* __restrict__ Vtp,
                    unsigned short* __restrict__ opart,
                    float* __restrict__ mlpart,
                    float* __restrict__ out,
                    int lg, int njt)
{
    __shared__ unsigned short KhL[2][32][64];
    __shared__ unsigned short KrL[2][32][64];

    const int jsp = 1 << lg;
    // XCD grouping: heads of one (b,i0,jspq) share one XCD's L2 seg region
    const int F = blockIdx.x;            // 512*jsp blocks
    const int x = F & 7;
    const int k = F >> 3;
    const int n = k & 15;
    const int g = ((k >> 4) << 3) + x;   // 0..32*jsp-1
    const int jspq = g & (jsp - 1);
    const int t2 = g >> lg;              // 0..31
    const int b  = t2 & 1;
    const int i0 = (t2 >> 1) * BLK_I;
    const int bn = n * 2 + b;            // matches pack layout
    const int boff = b * NHEAD * DHEAD + n * DHEAD;

    const int tid  = threadIdx.x;
    const int wave = tid >> 6;
    const int lane = tid & 63;
    const int q4   = lane >> 4;
    const int c    = lane & 15;
    const int iRow = i0 + wave * 16 + c;

    // ---- Q fragments (SC2f folded) + in-lane ef0 ----
    s16x8 qwf[2], qrf[2];
    float e0, e1;
    {
        const float* qp = q + (size_t)iRow * RS + boff;
        float es0 = 0.f, es1 = 0.f;
#pragma unroll
        for (int kk = 0; kk < 2; ++kk) {
            const int off = kk * 32 + q4 * 8;
            const f32x4 q0 = *(const f32x4*)(qp + off);
            const f32x4 q1 = *(const f32x4*)(qp + off + 4);
            const f32x4 w0 = *(const f32x4*)(rwb + n * DHEAD + off);
            const f32x4 w1 = *(const f32x4*)(rwb + n * DHEAD + off + 4);
            const f32x4 r0 = *(const f32x4*)(rrb + n * DHEAD + off);
            const f32x4 r1 = *(const f32x4*)(rrb + n * DHEAD + off + 4);
            const f32x4 sa = *(const f32x4*)(segemb + n * DHEAD + off);
            const f32x4 sb = *(const f32x4*)(segemb + n * DHEAD + off + 4);
            const f32x4 ta = *(const f32x4*)(segemb + (NHEAD + n) * DHEAD + off);
            const f32x4 tb = *(const f32x4*)(segemb + (NHEAD + n) * DHEAD + off + 4);
            const f32x4 ra = *(const f32x4*)(rsb + n * DHEAD + off);
            const f32x4 rb = *(const f32x4*)(rsb + n * DHEAD + off + 4);
            s16x8 tw, tr;
#pragma unroll
            for (int e = 0; e < 4; ++e) {
                tw[e]     = (short)f2bf((q0[e] + w0[e]) * SC2f);
                tw[4 + e] = (short)f2bf((q1[e] + w1[e]) * SC2f);
                tr[e]     = (short)f2bf((q0[e] + r0[e]) * SC2f);
                tr[4 + e] = (short)f2bf((q1[e] + r1[e]) * SC2f);
                es0 += (q0[e] + ra[e]) * sa[e] + (q1[e] + rb[e]) * sb[e];
                es1 += (q0[e] + ra[e]) * ta[e] + (q1[e] + rb[e]) * tb[e];
            }
            qwf[kk] = tw; qrf[kk] = tr;
        }
        es0 += __shfl_xor(es0, 16, 64); es0 += __shfl_xor(es0, 32, 64);
        es1 += __shfl_xor(es1, 16, 64); es1 += __shfl_xor(es1, 32, 64);
        e0 = es0 * SC2f; e1 = es1 * SC2f;
    }

    const int tbase = bn * NT32 + jspq * njt;
    auto stage = [&](int jt, int buf) {
        const size_t toff = ((size_t)(tbase + jt)) << 12;
        const int go = tid * 16;
        const int lo = wave * 1024;
        gl_lds16((const char*)Kp  + toff + go, (char*)&KhL[buf][0][0] + lo);
        gl_lds16((const char*)Krp + toff + go, (char*)&KrL[buf][0][0] + lo);
    };

    stage(0, 0);
    __syncthreads();

    float m = -INFINITY, lsum = 0.f;
    f32x4 acc[4];
#pragma unroll
    for (int dt = 0; dt < 4; ++dt) acc[dt] = (f32x4)0.f;

    // per-wave coalesced seg subtile base: (b, istrip = i0/16 + wave)
    const unsigned short* segW = segT + ((size_t)(b * 64 + (i0 >> 4) + wave) << 16);

    int cur = 0;
    for (int jt = 0; jt < njt; ++jt) {
        if (jt + 1 < njt) stage(jt + 1, cur ^ 1);   // K/Kr DMA flies under compute

        // ---- seg/mask: 4 coalesced 1KB wave-loads ----
        const unsigned short* st = segW + ((jspq * njt + jt) << 11);
        u16x8 pg[4];
        pg[0] = *(const u16x8*)(st + lane * 8);
        pg[1] = *(const u16x8*)(st + 512 + lane * 8);
        pg[2] = *(const u16x8*)(st + 1024 + lane * 8);
        pg[3] = *(const u16x8*)(st + 1536 + lane * 8);

        // ---- V fragments straight from global (consumption-order pack) ----
        const unsigned short* vtb = Vtp + (((size_t)(tbase + jt)) << 11);
        u16x8 vg[4];
#pragma unroll
        for (int dt = 0; dt < 4; ++dt)
            vg[dt] = *(const u16x8*)(vtb + ((dt << 6) + lane) * 8);

        // ---- S^T = (Kh Qw^T + Kr Qr^T): D[j][i], lane holds row i=c ----
        f32x4 sjT[2];
        sjT[0] = (f32x4)0.f; sjT[1] = (f32x4)0.f;
        __builtin_amdgcn_s_setprio(1);
#pragma unroll
        for (int kk = 0; kk < 2; ++kk)
#pragma unroll
            for (int js = 0; js < 2; ++js) {
                const int row = js * 16 + c;
                const int pcK = ((kk * 4 + q4) ^ (c & 7)) * 8;
                const s16x8 khf = *(const s16x8*)&KhL[cur][row][pcK];
                const s16x8 krf = *(const s16x8*)&KrL[cur][row][pcK];
                sjT[js] = __builtin_amdgcn_mfma_f32_16x16x32_bf16(khf, qwf[kk], sjT[js], 0, 0, 0);
                sjT[js] = __builtin_amdgcn_mfma_f32_16x16x32_bf16(krf, qrf[kk], sjT[js], 0, 0, 0);
            }
        __builtin_amdgcn_s_setprio(0);

        // ---- bias (SC2f pre-folded) ----
        float sc8[8];
#pragma unroll
        for (int js = 0; js < 2; ++js)
#pragma unroll
            for (int r = 0; r < 4; ++r) {
                const u16x8 g2 = pg[js * 2 + (r >> 1)];
                const int bb = (r & 1) * 4;
                sc8[js * 4 + r] = sjT[js][r]
                                  + bf2f(g2[bb]) * e0 + bf2f(g2[bb + 1]) * e1
                                  - bf2f(g2[bb + 2]);
            }
        float pmax = fmaxf(
            fmaxf(fmaxf(sc8[0], sc8[1]), fmaxf(sc8[2], sc8[3])),
            fmaxf(fmaxf(sc8[4], sc8[5]), fmaxf(sc8[6], sc8[7])));

        // ---- defer-max (T13) ----
        if (!__all(pmax <= m + THRf)) {
            float mt = pmax;
            mt = fmaxf(mt, __shfl_xor(mt, 16, 64));
            mt = fmaxf(mt, __shfl_xor(mt, 32, 64));
            const float mn  = fmaxf(m, mt);
            const float scl = __builtin_amdgcn_exp2f(m - mn);
            m = mn;
            lsum *= scl;
#pragma unroll
            for (int dt = 0; dt < 4; ++dt) acc[dt] *= scl;
        }

        // ---- P = exp2(sc - m) ----
        float p[8], ps = 0.f;
#pragma unroll
        for (int e = 0; e < 8; ++e) {
            p[e] = __builtin_amdgcn_exp2f(sc8[e] - m);
            ps += p[e];
        }
        lsum += ps;   // per-lane q4-partial; reduced at epilogue

        // ---- zero-exchange PV (k=16), V operand already in registers ----
        s16x4 pf4[2];
#pragma unroll
        for (int js = 0; js < 2; ++js) {
            union { unsigned int w[2]; s16x4 v; } pk2;
            asm("v_cvt_pk_bf16_f32 %0, %1, %2" : "=v"(pk2.w[0]) : "v"(p[js*4+0]), "v"(p[js*4+1]));
            asm("v_cvt_pk_bf16_f32 %0, %1, %2" : "=v"(pk2.w[1]) : "v"(p[js*4+2]), "v"(p[js*4+3]));
            pf4[js] = pk2.v;
        }
        __builtin_amdgcn_s_setprio(1);
#pragma unroll
        for (int dt = 0; dt < 4; ++dt) {
            union { u16x8 w; s16x4 h[2]; } vv; vv.w = vg[dt];
#pragma unroll
            for (int js = 0; js < 2; ++js)
                acc[dt] = mfma16x16x16(vv.h[js], pf4[js], acc[dt]);
        }
        __builtin_amdgcn_s_setprio(0);

        __syncthreads();   // drains DMA + all waves done with buf[cur]
        cur ^= 1;
    }

    // ---- full-row lsum (reduce over q4 groups) ----
    lsum += __shfl_xor(lsum, 16, 64);
    lsum += __shfl_xor(lsum, 32, 64);

    // ---- store ----
    if (lg) {
        const int rowG = ((jspq * BSZ + b) * NHEAD + n) * QLEN + iRow;
#pragma unroll
        for (int dt = 0; dt < 4; ++dt) {
            u16x4 ob;
#pragma unroll
            for (int e = 0; e < 4; ++e) ob[e] = f2bf(acc[dt][e]);
            *(u16x4*)&opart[(size_t)rowG * 64 + dt * 16 + q4 * 4] = ob;
        }
        if (q4 == 0) {
            mlpart[(size_t)rowG * 2]     = m;
            mlpart[(size_t)rowG * 2 + 1] = lsum;
        }
    } else {
        const float inv = 1.f / lsum;
        float* op = out + (size_t)iRow * RS + boff;
#pragma unroll
        for (int dt = 0; dt < 4; ++dt) {
            const f32x4 o = acc[dt] * inv;
            *(f32x4*)&op[dt * 16 + q4 * 4] = o;
        }
    }
}

extern "C" void kernel_launch(void* const* d_in, const int* in_sizes, int n_in,
                              void* d_out, int out_size, void* d_ws, size_t ws_size,
                              hipStream_t stream) {
    const float* q   = (const float*)d_in[0];
    const float* kh  = (const float*)d_in[1];
    const float* v   = (const float*)d_in[2];
    const float* kr  = (const float*)d_in[3];
    const float* se  = (const float*)d_in[4];
    const float* sm  = (const float*)d_in[5];
    const float* rwb = (const float*)d_in[6];
    const float* rrb = (const float*)d_in[7];
    const float* rsb = (const float*)d_in[8];
    const float* msk = (const float*)d_in[9];
    float* out = (float*)d_out;

    char* wsb = (char*)d_ws;
    unsigned short* segT = (unsigned short*)wsb;
    unsigned short* Kp   = (unsigned short*)(wsb + SEGP_BYTES);
    unsigned short* Krp  = (unsigned short*)(wsb + SEGP_BYTES + KT_BYTES);
    unsigned short* Vtp  = (unsigned short*)(wsb + SEGP_BYTES + 2 * KT_BYTES);
    unsigned short* opart = (unsigned short*)(wsb + SEGP_BYTES + 3 * KT_BYTES);

    const size_t base = (size_t)SEGP_BYTES + 3 * KT_BYTES;
    int lg = 0;
    if (ws_size >= base + 2 * ((size_t)OPART1_BYTES + ML1_BYTES)) lg = 1;
    const int jsp = 1 << lg;
    const int njt = NT32 >> lg;
    float* mlpart = (float*)(wsb + base + (size_t)jsp * OPART1_BYTES);

    pack_all_kernel<<<2048 + NBN * NT32, 256, 0, stream>>>(sm, msk, kh, kr, v,
                                                           segT, Kp, Krp, Vtp);
    relattn_kernel<<<512 * jsp, 256, 0, stream>>>(q, se, rwb, rrb, rsb,
                                                  segT, Kp, Krp, Vtp,
                                                  opart, mlpart, out, lg, njt);
    if (lg)
        merge_kernel<<<NQ * DHEAD / 256, 256, 0, stream>>>(opart, mlpart, out, jsp);
}

// Round 24
// 55.995 us; speedup vs baseline: 3.1607x; 1.0803x over previous
//
#include <hip/hip_runtime.h>

#define QLEN 1024
#define KLEN 1024
#define BSZ 2
#define NHEAD 16
#define DHEAD 64
#define RS 2048            /* BSZ*NHEAD*DHEAD floats per seq row */
#define BLK_I 64
#define BLK_J 32
#define NT32 (KLEN / BLK_J)   /* 32 tiles per bn */
#define NBN (BSZ * NHEAD)

#define SC2f  0.18033688011112440f   /* 0.125 * log2(e) */
#define MBIGf 1.4426950408889634e30f /* 1e30 * log2(e)  */
#define THRf  8.0f                   /* defer-max threshold (log2 units) */

#define SEGP_BYTES  16777216u                     /* 2*64*32 subtiles x 4KB */
#define KT_BYTES    ((size_t)NBN * NT32 * 4096)   /* 4 MiB per tensor */

typedef __attribute__((ext_vector_type(8))) short s16x8;
typedef __attribute__((ext_vector_type(4))) short s16x4;
typedef __attribute__((ext_vector_type(8))) unsigned short u16x8;
typedef __attribute__((ext_vector_type(4))) unsigned short u16x4;
typedef __attribute__((ext_vector_type(4))) float f32x4;
typedef __attribute__((ext_vector_type(2))) float f32x2;

__device__ __forceinline__ unsigned short f2bf(float f) {
    union { float f; unsigned int u; } x; x.f = f;
    unsigned int r = x.u + 0x7fffu + ((x.u >> 16) & 1u);
    return (unsigned short)(r >> 16);
}
__device__ __forceinline__ float bf2f(unsigned short h) {
    union { unsigned int u; float f; } x; x.u = ((unsigned int)h) << 16;
    return x.f;
}

__device__ __forceinline__ f32x4 mfma16x16x16(s16x4 a, s16x4 b, f32x4 c) {
#if __has_builtin(__builtin_amdgcn_mfma_f32_16x16x16bf16_1k)
    return __builtin_amdgcn_mfma_f32_16x16x16bf16_1k(a, b, c, 0, 0, 0);
#else
    f32x4 d;
    asm("v_mfma_f32_16x16x16_bf16 %0, %1, %2, %3"
        : "=v"(d) : "v"(a), "v"(b), "0"(c));
    return d;
#endif
}

typedef const __attribute__((address_space(1))) unsigned int* gas_t;
typedef __attribute__((address_space(3))) unsigned int* las_t;
__device__ __forceinline__ void gl_lds16(const void* g, void* l) {
    __builtin_amdgcn_global_load_lds((gas_t)g, (las_t)l, 16, 0, 0);
}

// ---- fused pre-pass (round-18/19 verbatim, passed) --------------------------
__global__ __launch_bounds__(256)
void pack_all_kernel(const float* __restrict__ segmat,
                     const float* __restrict__ mask,
                     const float* __restrict__ kh,
                     const float* __restrict__ kr,
                     const float* __restrict__ v,
                     unsigned short* __restrict__ segT,
                     unsigned short* __restrict__ Kp,
                     unsigned short* __restrict__ Krp,
                     unsigned short* __restrict__ Vtp)
{
    __shared__ float smS[16][32][4];
    __shared__ float smM[16][33];
    __shared__ float VT[32][65];
    const int bid = blockIdx.x;
    const int tid = threadIdx.x;

    if (bid < 2048) {
        const int istrip = bid >> 5;
        const int jt     = bid & 31;
        const int ib     = istrip * 16;
        const int jb     = jt * 32;
        {
            const int il = tid >> 4;
            const int j2 = (tid & 15) * 2;
            const float* sp = segmat + ((size_t)(ib + il) * KLEN + jb + j2) * 4;
            *(f32x4*)&smS[il][j2][0]     = *(const f32x4*)sp;
            *(f32x4*)&smS[il][j2 + 1][0] = *(const f32x4*)(sp + 4);
            const float* mp = mask + (size_t)(ib + il) * KLEN + jb + j2;
            smM[il][j2]     = mp[0] * MBIGf;
            smM[il][j2 + 1] = mp[1] * MBIGf;
        }
        __syncthreads();
        const int k  = tid >> 6;
        const int l  = tid & 63;
        const int q4 = l >> 4;
        const int il = l & 15;
        const int jl = (k >> 1) * 16 + q4 * 4 + (k & 1) * 2;
#pragma unroll
        for (int b = 0; b < 2; ++b) {
            u16x8 o;
#pragma unroll
            for (int e = 0; e < 2; ++e) {
                o[e * 4 + 0] = f2bf(smS[il][jl + e][b * 2]);
                o[e * 4 + 1] = f2bf(smS[il][jl + e][b * 2 + 1]);
                o[e * 4 + 2] = f2bf(smM[il][jl + e]);
                o[e * 4 + 3] = 0;
            }
            unsigned short* op = segT + ((size_t)(b * 64 + istrip) << 16)
                                 + (jt << 11) + tid * 8;
            *(u16x8*)op = o;
        }
    } else {
        const int blk = bid - 2048;               // bn*NT32 + jt
        const int bn  = blk >> 5;
        const int jt  = blk & (NT32 - 1);
        const int b   = bn & 1;
        const int n   = bn >> 1;
        const int boff = b * NHEAD * DHEAD + n * DHEAD;
        const int j0  = jt * BLK_J;

        {
            const int j  = tid >> 3;
            const int dq = (tid & 7) * 8;
            const float* vp = v + (size_t)(j0 + j) * RS + boff + dq;
#pragma unroll
            for (int e = 0; e < 8; ++e) VT[j][dq + e] = vp[e];
        }
        __syncthreads();

        const size_t tb = (size_t)blk * 2048;
        {
            const int row = tid >> 3;
            const int ch  = (tid & 7) ^ (row & 7);
            u16x8 ok, orr;
            const float* hp = kh + (size_t)(j0 + row) * RS + boff + ch * 8;
            const float* rp = kr + (size_t)(j0 + row + 1) * RS + boff + ch * 8; // shift +1
#pragma unroll
            for (int e = 0; e < 8; ++e) { ok[e] = f2bf(hp[e]); orr[e] = f2bf(rp[e]); }
            *(u16x8*)&Kp [tb + (size_t)tid * 8] = ok;
            *(u16x8*)&Krp[tb + (size_t)tid * 8] = orr;
        }
        {   // V^T: row d, two 8B granules per thread; phys8 = gj8 ^ (d&7)
            const int d  = tid >> 2;
            const int gl = tid & 3;
#pragma unroll
            for (int s = 0; s < 2; ++s) {
                const int gj8 = gl * 2 + s;
                const int ph  = gj8 ^ (d & 7);
                u16x4 ov;
#pragma unroll
                for (int e = 0; e < 4; ++e) ov[e] = f2bf(VT[gj8 * 4 + e][d]);
                *(u16x4*)&Vtp[tb + (size_t)d * 32 + ph * 4] = ov;
            }
        }
    }
}

// ---- main: BLK_I=64, 8 waves (4 ih x 2 jh), 512 blocks, no merge kernel -----
__global__ __launch_bounds__(512, 4)
void relattn_kernel(const float* __restrict__ q,
                    const float* __restrict__ segemb,
                    const float* __restrict__ rwb,
                    const float* __restrict__ rrb,
                    const float* __restrict__ rsb,
                    const unsigned short* __restrict__ segT,
                    const unsigned short* __restrict__ Kp,
                    const unsigned short* __restrict__ Krp,
                    const unsigned short* __restrict__ Vtp,
                    float* __restrict__ out)
{
    __shared__ unsigned short KhL[2][32][64];
    __shared__ unsigned short KrL[2][32][64];
    __shared__ unsigned short VtL[2][64][32];

    // XCD grouping (R15/R16): 16 heads of one (b,i0) share an XCD's L2 segT
    const int F = blockIdx.x;            // 512 blocks
    const int x = F & 7;
    const int k = F >> 3;                // 0..63
    const int g = (k >> 4) * 8 + x;      // (b,i0) group id
    const int n = k & 15;
    const int i0 = (g >> 1) * BLK_I;
    const int b  = g & 1;
    const int bn = n * 2 + b;            // matches pack layout
    const int boff = b * NHEAD * DHEAD + n * DHEAD;

    const int tid  = threadIdx.x;
    const int wave = tid >> 6;           // 0..7
    const int lane = tid & 63;
    const int q4   = lane >> 4;
    const int c    = lane & 15;
    const int ih   = wave >> 1;          // 0..3: i-strip of 16 rows
    const int jh   = wave & 1;           // 0/1: j-half of each 32-j tile
    const int iRow = i0 + ih * 16 + c;

    // ---- Q fragments + in-lane ef0 ----
    s16x8 qwf[2], qrf[2];
    float e0, e1;
    {
        const float* qp = q + (size_t)iRow * RS + boff;
        float es0 = 0.f, es1 = 0.f;
#pragma unroll
        for (int kk = 0; kk < 2; ++kk) {
            const int off = kk * 32 + q4 * 8;
            const f32x4 q0 = *(const f32x4*)(qp + off);
            const f32x4 q1 = *(const f32x4*)(qp + off + 4);
            const f32x4 w0 = *(const f32x4*)(rwb + n * DHEAD + off);
            const f32x4 w1 = *(const f32x4*)(rwb + n * DHEAD + off + 4);
            const f32x4 r0 = *(const f32x4*)(rrb + n * DHEAD + off);
            const f32x4 r1 = *(const f32x4*)(rrb + n * DHEAD + off + 4);
            const f32x4 sa = *(const f32x4*)(segemb + n * DHEAD + off);
            const f32x4 sb = *(const f32x4*)(segemb + n * DHEAD + off + 4);
            const f32x4 ta = *(const f32x4*)(segemb + (NHEAD + n) * DHEAD + off);
            const f32x4 tb = *(const f32x4*)(segemb + (NHEAD + n) * DHEAD + off + 4);
            const f32x4 ra = *(const f32x4*)(rsb + n * DHEAD + off);
            const f32x4 rb = *(const f32x4*)(rsb + n * DHEAD + off + 4);
            s16x8 tw, tr;
#pragma unroll
            for (int e = 0; e < 4; ++e) {
                tw[e]     = (short)f2bf(q0[e] + w0[e]);
                tw[4 + e] = (short)f2bf(q1[e] + w1[e]);
                tr[e]     = (short)f2bf(q0[e] + r0[e]);
                tr[4 + e] = (short)f2bf(q1[e] + r1[e]);
                es0 += (q0[e] + ra[e]) * sa[e] + (q1[e] + rb[e]) * sb[e];
                es1 += (q0[e] + ra[e]) * ta[e] + (q1[e] + rb[e]) * tb[e];
            }
            qwf[kk] = tw; qrf[kk] = tr;
        }
        es0 += __shfl_xor(es0, 16, 64); es0 += __shfl_xor(es0, 32, 64);
        es1 += __shfl_xor(es1, 16, 64); es1 += __shfl_xor(es1, 32, 64);
        e0 = es0 * SC2f; e1 = es1 * SC2f;
    }

    // ---- async DMA staging: waves 0-3 -> K+Kr (1KB each), waves 4-7 -> V ----
    const int tbase = bn * NT32;
    auto stage = [&](int jt, int buf) {
        const size_t toff = ((size_t)(tbase + jt)) << 12;
        if (wave < 4) {
            const int lo = wave * 1024;
            const int go = lo + lane * 16;
            gl_lds16((const char*)Kp  + toff + go, (char*)&KhL[buf][0][0] + lo);
            gl_lds16((const char*)Krp + toff + go, (char*)&KrL[buf][0][0] + lo);
        } else {
            const int lo = (wave - 4) * 1024;
            const int go = lo + lane * 16;
            gl_lds16((const char*)Vtp + toff + go, (char*)&VtL[buf][0][0] + lo);
        }
    };

    stage(0, 0);
    __syncthreads();

    float m = -INFINITY, lsum = 0.f;
    f32x4 acc[4];
#pragma unroll
    for (int dt = 0; dt < 4; ++dt) acc[dt] = (f32x4)0.f;

    // per-wave seg subtile base: (b, istrip = i0/16 + ih)
    const unsigned short* segW = segT + ((size_t)(b * 64 + (i0 >> 4) + ih) << 16);

    int cur = 0;
    for (int jt = 0; jt < NT32; ++jt) {
        if (jt + 1 < NT32) stage(jt + 1, cur ^ 1);   // DMA flies under compute

        // ---- seg/mask: 2 coalesced 1KB wave-loads (k = jh*2 + t) ----
        const unsigned short* st = segW + (jt << 11);
        u16x8 pg2[2];
        pg2[0] = *(const u16x8*)(st + (jh * 2 + 0) * 512 + lane * 8);
        pg2[1] = *(const u16x8*)(st + (jh * 2 + 1) * 512 + lane * 8);

        // ---- S^T quadrant = (Kh Qw^T + Kr Qr^T): rows j = jh*16 + q4*4+r ----
        f32x4 sjT = (f32x4)0.f;
        __builtin_amdgcn_s_setprio(1);
#pragma unroll
        for (int kk = 0; kk < 2; ++kk) {
            const int row = jh * 16 + c;
            const int pcK = ((kk * 4 + q4) ^ (c & 7)) * 8;
            const s16x8 khf = *(const s16x8*)&KhL[cur][row][pcK];
            const s16x8 krf = *(const s16x8*)&KrL[cur][row][pcK];
            sjT = __builtin_amdgcn_mfma_f32_16x16x32_bf16(khf, qwf[kk], sjT, 0, 0, 0);
            sjT = __builtin_amdgcn_mfma_f32_16x16x32_bf16(krf, qrf[kk], sjT, 0, 0, 0);
        }
        __builtin_amdgcn_s_setprio(0);

        // ---- bias: j = jh*16 + q4*4 + r ----
        float sc4[4];
#pragma unroll
        for (int r = 0; r < 4; ++r) {
            const u16x8 g2 = pg2[r >> 1];
            const int bb = (r & 1) * 4;
            sc4[r] = sjT[r] * SC2f
                     + bf2f(g2[bb]) * e0 + bf2f(g2[bb + 1]) * e1
                     - bf2f(g2[bb + 2]);
        }
        float pmax = fmaxf(fmaxf(sc4[0], sc4[1]), fmaxf(sc4[2], sc4[3]));

        // ---- defer-max (T13) ----
        if (!__all(pmax <= m + THRf)) {
            float mt = pmax;
            mt = fmaxf(mt, __shfl_xor(mt, 16, 64));
            mt = fmaxf(mt, __shfl_xor(mt, 32, 64));
            const float mn  = fmaxf(m, mt);
            const float scl = __builtin_amdgcn_exp2f(m - mn);
            m = mn;
            lsum *= scl;
#pragma unroll
            for (int dt = 0; dt < 4; ++dt) acc[dt] *= scl;
        }

        // ---- P = exp2(sc - m); zero-exchange PV (k=16, single B-frag) ----
        float p[4], ps = 0.f;
#pragma unroll
        for (int e = 0; e < 4; ++e) {
            p[e] = __builtin_amdgcn_exp2f(sc4[e] - m);
            ps += p[e];
        }
        lsum += ps;   // per-lane q4-partial; reduced at epilogue

        s16x4 pf4;
        {
            union { unsigned int w[2]; s16x4 v; } pk2;
            asm("v_cvt_pk_bf16_f32 %0, %1, %2" : "=v"(pk2.w[0]) : "v"(p[0]), "v"(p[1]));
            asm("v_cvt_pk_bf16_f32 %0, %1, %2" : "=v"(pk2.w[1]) : "v"(p[2]), "v"(p[3]));
            pf4 = pk2.v;
        }
        __builtin_amdgcn_s_setprio(1);
#pragma unroll
        for (int dt = 0; dt < 4; ++dt) {
            // A-frag (V^T): row d = dt*16+c, k = j = jh*16 + q4*4 + e;
            // 8B granule gj8 = jh*4+q4, phys = gj8 ^ (d&7) = gj8 ^ (c&7)
            const int ph = (jh * 4 + q4) ^ (c & 7);
            const s16x4 vf = *(const s16x4*)&VtL[cur][dt * 16 + c][ph * 4];
            acc[dt] = mfma16x16x16(vf, pf4, acc[dt]);
        }
        __builtin_amdgcn_s_setprio(0);

        __syncthreads();   // drains DMA + all waves done with buf[cur]
        cur ^= 1;
    }

    // ---- full-row lsum (reduce over q4 groups) ----
    lsum += __shfl_xor(lsum, 16, 64);
    lsum += __shfl_xor(lsum, 32, 64);

    // ---- jh merge via LDS (pairs: same ih, jh 0/1), then store ----
    __syncthreads();
    float* scrO  = (float*)&KhL[0][0][0];                 // [64][68] f32 (17.4KB)
    float* scrML = (float*)((char*)&VtL[0][0][0] + 2048); // [64][2]   (512B)
    if (jh == 1) {
        const int rowL = ih * 16 + c;                     // 0..63
#pragma unroll
        for (int dt = 0; dt < 4; ++dt)
            *(f32x4*)&scrO[rowL * 68 + dt * 16 + q4 * 4] = acc[dt];
        if (q4 == 0) {
            scrML[rowL * 2]     = m;
            scrML[rowL * 2 + 1] = lsum;
        }
    }
    __syncthreads();
    if (jh == 0) {
        const int rowL = ih * 16 + c;
        const float m1 = scrML[rowL * 2];
        const float l1 = scrML[rowL * 2 + 1];
        const float M  = fmaxf(m, m1);
        const float w0 = __builtin_amdgcn_exp2f(m - M);
        const float w1 = __builtin_amdgcn_exp2f(m1 - M);
        const float inv = 1.f / (lsum * w0 + l1 * w1);
        float* op = out + (size_t)iRow * RS + boff;
#pragma unroll
        for (int dt = 0; dt < 4; ++dt) {
            const f32x4 o = (acc[dt] * w0
                          + (*(const f32x4*)&scrO[rowL * 68 + dt * 16 + q4 * 4]) * w1) * inv;
            *(f32x4*)&op[dt * 16 + q4 * 4] = o;
        }
    }
}

extern "C" void kernel_launch(void* const* d_in, const int* in_sizes, int n_in,
                              void* d_out, int out_size, void* d_ws, size_t ws_size,
                              hipStream_t stream) {
    const float* q   = (const float*)d_in[0];
    const float* kh  = (const float*)d_in[1];
    const float* v   = (const float*)d_in[2];
    const float* kr  = (const float*)d_in[3];
    const float* se  = (const float*)d_in[4];
    const float* sm  = (const float*)d_in[5];
    const float* rwb = (const float*)d_in[6];
    const float* rrb = (const float*)d_in[7];
    const float* rsb = (const float*)d_in[8];
    const float* msk = (const float*)d_in[9];
    float* out = (float*)d_out;

    char* wsb = (char*)d_ws;   // needs 16.8 + 12.6 = 29.4 MB
    unsigned short* segT = (unsigned short*)wsb;
    unsigned short* Kp   = (unsigned short*)(wsb + SEGP_BYTES);
    unsigned short* Krp  = (unsigned short*)(wsb + SEGP_BYTES + KT_BYTES);
    unsigned short* Vtp  = (unsigned short*)(wsb + SEGP_BYTES + 2 * KT_BYTES);

    pack_all_kernel<<<2048 + NBN * NT32, 256, 0, stream>>>(sm, msk, kh, kr, v,
                                                           segT, Kp, Krp, Vtp);
    relattn_kernel<<<512, 512, 0, stream>>>(q, se, rwb, rrb, rsb,
                                            segT, Kp, Krp, Vtp, out);
}